// Round 1
// baseline (1920.764 us; speedup 1.0000x reference)
//
#include <hip/hip_runtime.h>
#include <hip/hip_bf16.h>

// ---------------------------------------------------------------------------
// GCN forward: 4x (gemm -> sym-norm aggregate -> +b -> relu), scalar 5th conv,
// mean-pool heads, masked softmax.  All fp32.
// ---------------------------------------------------------------------------

#define WAVE 64

// ---------------- small helpers ----------------
__device__ __forceinline__ float waveSum(float v) {
  #pragma unroll
  for (int o = 32; o; o >>= 1) v += __shfl_xor(v, o);
  return v;
}
__device__ __forceinline__ float waveMax(float v) {
  #pragma unroll
  for (int o = 32; o; o >>= 1) v = fmaxf(v, __shfl_xor(v, o));
  return v;
}
__device__ __forceinline__ unsigned encf(float f) {
  unsigned u = __float_as_uint(f);
  return (u & 0x80000000u) ? ~u : (u | 0x80000000u);
}
__device__ __forceinline__ float decf(unsigned e) {
  unsigned u = (e & 0x80000000u) ? (e & 0x7fffffffu) : ~e;
  return __uint_as_float(u);
}

// ---------------- init ----------------
__global__ void init_red(float* __restrict__ red) {
  int t = threadIdx.x;
  if (t < 64) red[t] = 0.f;                       // x_mean accumulators
  if (t == 65) ((unsigned*)red)[65] = 0u;         // encoded max (0 == -inf)
  if (t == 66) red[66] = 0.f;                     // sumexp
}

// ---------------- degree histogram ----------------
__global__ void hist_k(const int* __restrict__ ei, int* __restrict__ ihist, int E) {
  int e = blockIdx.x * blockDim.x + threadIdx.x;
  if (e < E) atomicAdd(&ihist[ei[e]], 1);         // row = ei[e]
}

__global__ void dinv_k(const int* __restrict__ ihist, float* __restrict__ dinv, int N) {
  int i = blockIdx.x * blockDim.x + threadIdx.x;
  if (i < N) dinv[i] = 1.0f / sqrtf((float)(ihist[i] + 1));   // +1 self-loop
}

// ---------------- exclusive scan (3 kernels), 1024 elems / block ----------------
__global__ void scan_blocks(const int* __restrict__ ihist, int* __restrict__ row_ptr,
                            int* __restrict__ bsums, int N) {
  __shared__ int sh[256];
  int t = threadIdx.x;
  int base = blockIdx.x * 1024;
  int v[4];
  #pragma unroll
  for (int j = 0; j < 4; ++j) {
    int idx = base + t * 4 + j;
    v[j] = (idx < N) ? ihist[idx] : 0;
  }
  int local = v[0] + v[1] + v[2] + v[3];
  sh[t] = local;
  __syncthreads();
  for (int o = 1; o < 256; o <<= 1) {
    int x = (t >= o) ? sh[t - o] : 0;
    __syncthreads();
    sh[t] += x;
    __syncthreads();
  }
  int run = sh[t] - local;   // exclusive prefix of this thread's chunk
  #pragma unroll
  for (int j = 0; j < 4; ++j) {
    int idx = base + t * 4 + j;
    if (idx < N) row_ptr[idx] = run;
    run += v[j];
  }
  if (t == 255) bsums[blockIdx.x] = sh[255];
}

__global__ void scan_sums(int* __restrict__ bsums, int NB) {
  __shared__ int sh[256];
  int t = threadIdx.x;
  int v = (t < NB) ? bsums[t] : 0;
  sh[t] = v;
  __syncthreads();
  for (int o = 1; o < 256; o <<= 1) {
    int x = (t >= o) ? sh[t - o] : 0;
    __syncthreads();
    sh[t] += x;
    __syncthreads();
  }
  if (t < NB) bsums[t] = sh[t] - v;   // exclusive
}

__global__ void scan_add(int* __restrict__ row_ptr, const int* __restrict__ bsums,
                         int N, int E) {
  int i = blockIdx.x * blockDim.x + threadIdx.x;
  if (i < N) row_ptr[i] += bsums[i >> 10];
  if (i == N) row_ptr[N] = E;
}

// ---------------- CSR build ----------------
__global__ void build_csr(const int* __restrict__ ei, const int* __restrict__ row_ptr,
                          int* __restrict__ fill, const float* __restrict__ dinv,
                          int* __restrict__ col_s, float* __restrict__ norm_s, int E) {
  int e = blockIdx.x * blockDim.x + threadIdx.x;
  if (e >= E) return;
  int r = ei[e];
  int c = ei[E + e];
  int p = row_ptr[r] + atomicAdd(&fill[r], 1);
  col_s[p] = c;
  norm_s[p] = dinv[r] * dinv[c];
}

// ---------------- GEMM: Y[N][64] = X[N][K] @ W[K][64] ----------------
template <int K, int RPT>   // rows per block = 16*RPT
__global__ __launch_bounds__(256) void gemm_nn(const float* __restrict__ X,
                                               const float* __restrict__ Wg,
                                               float* __restrict__ Y, int N) {
  constexpr int ROWS = 16 * RPT;
  __shared__ float ws[K * 64];
  __shared__ float xs[ROWS][K + 4];
  int t = threadIdx.x;
  int r0 = blockIdx.x * ROWS;
  for (int idx = t; idx < K * 64; idx += 256) ws[idx] = Wg[idx];
  for (int idx = t; idx < ROWS * K; idx += 256) {
    int r = idx / K, k = idx - r * K;
    int gr = r0 + r;
    xs[r][k] = (gr < N) ? X[(size_t)gr * K + k] : 0.f;
  }
  __syncthreads();
  int cg = t & 15;    // 16 col groups of 4
  int rg = t >> 4;    // 16 row groups of RPT
  float4 acc[RPT];
  #pragma unroll
  for (int i = 0; i < RPT; ++i) acc[i] = make_float4(0.f, 0.f, 0.f, 0.f);
  for (int k = 0; k < K; k += 4) {
    float4 wv0 = *(const float4*)&ws[(k + 0) * 64 + cg * 4];
    float4 wv1 = *(const float4*)&ws[(k + 1) * 64 + cg * 4];
    float4 wv2 = *(const float4*)&ws[(k + 2) * 64 + cg * 4];
    float4 wv3 = *(const float4*)&ws[(k + 3) * 64 + cg * 4];
    #pragma unroll
    for (int i = 0; i < RPT; ++i) {
      float4 xv = *(const float4*)&xs[rg * RPT + i][k];
      acc[i].x += xv.x * wv0.x + xv.y * wv1.x + xv.z * wv2.x + xv.w * wv3.x;
      acc[i].y += xv.x * wv0.y + xv.y * wv1.y + xv.z * wv2.y + xv.w * wv3.y;
      acc[i].z += xv.x * wv0.z + xv.y * wv1.z + xv.z * wv2.z + xv.w * wv3.z;
      acc[i].w += xv.x * wv0.w + xv.y * wv1.w + xv.z * wv2.w + xv.w * wv3.w;
    }
  }
  #pragma unroll
  for (int i = 0; i < RPT; ++i) {
    int gr = r0 + rg * RPT + i;
    if (gr < N) *(float4*)&Y[(size_t)gr * 64 + cg * 4] = acc[i];
  }
}

// ---------------- aggregation, H=64: one wave per node ----------------
__global__ __launch_bounds__(256) void agg64(const float* __restrict__ Y,
                                             const int* __restrict__ col_s,
                                             const float* __restrict__ norm_s,
                                             const int* __restrict__ row_ptr,
                                             const float* __restrict__ dinv,
                                             const float* __restrict__ bias,
                                             float* __restrict__ X, int relu, int N) {
  int i = blockIdx.x * 4 + (threadIdx.x >> 6);
  if (i >= N) return;
  int lane = threadIdx.x & 63;
  float di = dinv[i];
  float acc = di * di * Y[i * 64 + lane];
  float acc2 = 0.f;
  int p0 = row_ptr[i], p1 = row_ptr[i + 1];
  for (int base = p0; base < p1; base += 64) {
    int m = min(64, p1 - base);
    int c = 0; float nv = 0.f;
    if (lane < m) { c = col_s[base + lane]; nv = norm_s[base + lane]; }
    int j = 0;
    for (; j + 4 <= m; j += 4) {
      int c0 = __shfl(c, j),     c1 = __shfl(c, j + 1);
      int c2 = __shfl(c, j + 2), c3 = __shfl(c, j + 3);
      float n0 = __shfl(nv, j),     n1 = __shfl(nv, j + 1);
      float n2 = __shfl(nv, j + 2), n3 = __shfl(nv, j + 3);
      float y0 = Y[c0 * 64 + lane];
      float y1 = Y[c1 * 64 + lane];
      float y2 = Y[c2 * 64 + lane];
      float y3 = Y[c3 * 64 + lane];
      acc  += n0 * y0 + n1 * y1;
      acc2 += n2 * y2 + n3 * y3;
    }
    for (; j < m; ++j) {
      int cc = __shfl(c, j);
      float nn = __shfl(nv, j);
      acc += nn * Y[cc * 64 + lane];
    }
  }
  acc += acc2 + bias[lane];
  if (relu) acc = fmaxf(acc, 0.f);
  X[i * 64 + lane] = acc;
}

// ---------------- mean pooling partials ----------------
__global__ void mean_partial(const float* __restrict__ X, float* __restrict__ red, int N) {
  int lane = threadIdx.x & 63;
  int sub = threadIdx.x >> 6;     // 0..3
  int base = blockIdx.x * 1024;
  float s = 0.f;
  for (int r = sub; r < 1024; r += 4) {
    int row = base + r;
    if (row < N) s += X[row * 64 + lane];
  }
  __shared__ float sh[4][64];
  sh[sub][lane] = s;
  __syncthreads();
  if (sub == 0) {
    float t = sh[0][lane] + sh[1][lane] + sh[2][lane] + sh[3][lane];
    atomicAdd(&red[lane], t);
  }
}

// ---------------- h5 = X @ W5 (scalar per row) ----------------
__global__ void dot64(const float* __restrict__ X, const float* __restrict__ W5,
                      float* __restrict__ h5, int N) {
  int i = blockIdx.x * 4 + (threadIdx.x >> 6);
  if (i >= N) return;
  int lane = threadIdx.x & 63;
  float p = X[i * 64 + lane] * W5[lane];
  p = waveSum(p);
  if (lane == 0) h5[i] = p;
}

// ---------------- scalar aggregation (layer 5) ----------------
__global__ void agg_scalar(const float* __restrict__ h5, const int* __restrict__ col_s,
                           const float* __restrict__ norm_s, const int* __restrict__ row_ptr,
                           const float* __restrict__ dinv, const float* __restrict__ b5,
                           float* __restrict__ out, int N) {
  int i = blockIdx.x * blockDim.x + threadIdx.x;
  if (i >= N) return;
  float di = dinv[i];
  float acc = di * di * h5[i];
  int p1 = row_ptr[i + 1];
  for (int p = row_ptr[i]; p < p1; ++p) acc += norm_s[p] * h5[col_s[p]];
  out[i] = acc + b5[0];
}

// ---------------- heads: v and prob_nothing ----------------
__global__ void heads(const float* __restrict__ red, const float* __restrict__ Wv,
                      const float* __restrict__ bv, const float* __restrict__ Wdn,
                      const float* __restrict__ bdn, float* __restrict__ out, int N) {
  int lane = threadIdx.x;   // 64 threads
  float xm = red[lane] / (float)N;
  float pv = waveSum(xm * Wv[lane]);
  float pd = waveSum(xm * Wdn[lane]);
  if (lane == 0) {
    out[N] = pd + bdn[0];       // prob_nothing logit
    out[N + 1] = pv + bv[0];    // value head (final output slot)
  }
}

// ---------------- masked softmax over out[0..N] ----------------
__global__ void smax_max(const float* __restrict__ out, const int* __restrict__ ready,
                         float* __restrict__ red, int N) {
  int i = blockIdx.x * blockDim.x + threadIdx.x;
  float l = -3e38f;
  if (i < N) { if (ready[i]) l = out[i]; }
  else if (i == N) l = out[N];
  l = waveMax(l);
  __shared__ float sh[4];
  if (!(threadIdx.x & 63)) sh[threadIdx.x >> 6] = l;
  __syncthreads();
  if (threadIdx.x == 0) {
    float m = fmaxf(fmaxf(sh[0], sh[1]), fmaxf(sh[2], sh[3]));
    atomicMax(&((unsigned*)red)[65], encf(m));
  }
}

__global__ void smax_sum(const float* __restrict__ out, const int* __restrict__ ready,
                         float* __restrict__ red, int N) {
  float M = decf(((const unsigned*)red)[65]);
  int i = blockIdx.x * blockDim.x + threadIdx.x;
  float s = 0.f;
  if (i < N) { if (ready[i]) s = expf(out[i] - M); }
  else if (i == N) s = expf(out[N] - M);
  s = waveSum(s);
  __shared__ float sh[4];
  if (!(threadIdx.x & 63)) sh[threadIdx.x >> 6] = s;
  __syncthreads();
  if (threadIdx.x == 0) atomicAdd(&red[66], sh[0] + sh[1] + sh[2] + sh[3]);
}

__global__ void smax_write(float* __restrict__ out, const int* __restrict__ ready,
                           const float* __restrict__ red, int N) {
  float M = decf(((const unsigned*)red)[65]);
  float S = red[66];
  int i = blockIdx.x * blockDim.x + threadIdx.x;
  if (i < N) {
    out[i] = ready[i] ? (expf(out[i] - M) / S) : 0.f;
  } else if (i == N) {
    out[N] = expf(out[N] - M) / S;
  }
}

// ---------------------------------------------------------------------------
extern "C" void kernel_launch(void* const* d_in, const int* in_sizes, int n_in,
                              void* d_out, int out_size, void* d_ws, size_t ws_size,
                              hipStream_t stream) {
  const float* x    = (const float*)d_in[0];
  const int*   ei   = (const int*)d_in[1];
  const int*   ready= (const int*)d_in[2];
  const float* W1   = (const float*)d_in[3];
  const float* b1   = (const float*)d_in[4];
  const float* W2   = (const float*)d_in[5];
  const float* b2   = (const float*)d_in[6];
  const float* W3   = (const float*)d_in[7];
  const float* b3   = (const float*)d_in[8];
  const float* W4   = (const float*)d_in[9];
  const float* b4   = (const float*)d_in[10];
  const float* W5   = (const float*)d_in[11];
  const float* b5   = (const float*)d_in[12];
  const float* Wdn  = (const float*)d_in[13];
  const float* bdn  = (const float*)d_in[14];
  const float* Wv   = (const float*)d_in[15];
  const float* bv   = (const float*)d_in[16];
  float* out = (float*)d_out;

  int N = in_sizes[2];          // ready is (N,1)
  int E = in_sizes[1] / 2;      // edge_index is (2,E)

  // workspace carve (256B-aligned slices)
  char* base = (char*)d_ws;
  size_t off = 0;
  auto alloc = [&](size_t elems) -> void* {
    void* p = base + off;
    off += ((elems * 4 + 255) / 256) * 256;
    return p;
  };
  float* dinv   = (float*)alloc(N);
  int*   ihist  = (int*)alloc(N);
  int*   row_ptr= (int*)alloc((size_t)N + 1);
  int*   bsums  = (int*)alloc(256);
  int*   col_s  = (int*)alloc(E);
  float* norm_s = (float*)alloc(E);
  float* h5     = (float*)alloc(N);
  float* red    = (float*)alloc(128);
  float* Yb     = (float*)alloc((size_t)N * 64);
  float* Xb     = (float*)alloc((size_t)N * 64);
  (void)ws_size; (void)n_in; (void)out_size;

  int NB = (N + 1023) / 1024;
  int gE = (E + 255) / 256;
  int gN = (N + 255) / 256;
  int gN1 = (N + 1 + 255) / 256;
  int gW = (N + 3) / 4;         // wave-per-node grids

  hipMemsetAsync(ihist, 0, (size_t)N * 4, stream);
  init_red<<<1, 128, 0, stream>>>(red);
  hist_k<<<gE, 256, 0, stream>>>(ei, ihist, E);
  dinv_k<<<gN, 256, 0, stream>>>(ihist, dinv, N);
  scan_blocks<<<NB, 256, 0, stream>>>(ihist, row_ptr, bsums, N);
  scan_sums<<<1, 256, 0, stream>>>(bsums, NB);
  scan_add<<<gN1, 256, 0, stream>>>(row_ptr, bsums, N, E);
  hipMemsetAsync(ihist, 0, (size_t)N * 4, stream);
  build_csr<<<gE, 256, 0, stream>>>(ei, row_ptr, ihist, dinv, col_s, norm_s, E);

  // layer 1 (K = 128)
  gemm_nn<128, 2><<<(N + 31) / 32, 256, 0, stream>>>(x, W1, Yb, N);
  agg64<<<gW, 256, 0, stream>>>(Yb, col_s, norm_s, row_ptr, dinv, b1, Xb, 1, N);
  // layers 2-4 (K = 64)
  gemm_nn<64, 4><<<(N + 63) / 64, 256, 0, stream>>>(Xb, W2, Yb, N);
  agg64<<<gW, 256, 0, stream>>>(Yb, col_s, norm_s, row_ptr, dinv, b2, Xb, 1, N);
  gemm_nn<64, 4><<<(N + 63) / 64, 256, 0, stream>>>(Xb, W3, Yb, N);
  agg64<<<gW, 256, 0, stream>>>(Yb, col_s, norm_s, row_ptr, dinv, b3, Xb, 1, N);
  gemm_nn<64, 4><<<(N + 63) / 64, 256, 0, stream>>>(Xb, W4, Yb, N);
  agg64<<<gW, 256, 0, stream>>>(Yb, col_s, norm_s, row_ptr, dinv, b4, Xb, 1, N);

  // pooled heads + layer 5
  mean_partial<<<NB, 256, 0, stream>>>(Xb, red, N);
  dot64<<<gW, 256, 0, stream>>>(Xb, W5, h5, N);
  agg_scalar<<<gN, 256, 0, stream>>>(h5, col_s, norm_s, row_ptr, dinv, b5, out, N);
  heads<<<1, 64, 0, stream>>>(red, Wv, bv, Wdn, bdn, out, N);

  // masked softmax over out[0..N]
  smax_max<<<gN1, 256, 0, stream>>>(out, ready, red, N);
  smax_sum<<<gN1, 256, 0, stream>>>(out, ready, red, N);
  smax_write<<<gN1, 256, 0, stream>>>(out, ready, red, N);
}

// Round 2
// 1132.249 us; speedup vs baseline: 1.6964x; 1.6964x over previous
//
#include <hip/hip_runtime.h>
#include <hip/hip_bf16.h>

// ---------------------------------------------------------------------------
// GCN forward: 4x (gemm -> sym-norm aggregate -> +b -> relu), scalar 5th conv,
// mean-pool heads, masked softmax.  All fp32.
//
// R1 change: gemm_nn k-loop was fully unrolled by the compiler (32 iters for
// K=128), blowing the VGPR file (VGPR_Count=256) and spilling ~1.2KB/thread
// to scratch (WRITE_SIZE 990MB vs 26MB ideal, 615us for one GEMM).
// Fix: #pragma unroll 2 on the k-loop + __launch_bounds__(256,4) to cap
// VGPRs at 128.
// ---------------------------------------------------------------------------

#define WAVE 64

// ---------------- small helpers ----------------
__device__ __forceinline__ float waveSum(float v) {
  #pragma unroll
  for (int o = 32; o; o >>= 1) v += __shfl_xor(v, o);
  return v;
}
__device__ __forceinline__ float waveMax(float v) {
  #pragma unroll
  for (int o = 32; o; o >>= 1) v = fmaxf(v, __shfl_xor(v, o));
  return v;
}
__device__ __forceinline__ unsigned encf(float f) {
  unsigned u = __float_as_uint(f);
  return (u & 0x80000000u) ? ~u : (u | 0x80000000u);
}
__device__ __forceinline__ float decf(unsigned e) {
  unsigned u = (e & 0x80000000u) ? (e & 0x7fffffffu) : ~e;
  return __uint_as_float(u);
}

// ---------------- init ----------------
__global__ void init_red(float* __restrict__ red) {
  int t = threadIdx.x;
  if (t < 64) red[t] = 0.f;                       // x_mean accumulators
  if (t == 65) ((unsigned*)red)[65] = 0u;         // encoded max (0 == -inf)
  if (t == 66) red[66] = 0.f;                     // sumexp
}

// ---------------- degree histogram ----------------
__global__ void hist_k(const int* __restrict__ ei, int* __restrict__ ihist, int E) {
  int e = blockIdx.x * blockDim.x + threadIdx.x;
  if (e < E) atomicAdd(&ihist[ei[e]], 1);         // row = ei[e]
}

__global__ void dinv_k(const int* __restrict__ ihist, float* __restrict__ dinv, int N) {
  int i = blockIdx.x * blockDim.x + threadIdx.x;
  if (i < N) dinv[i] = 1.0f / sqrtf((float)(ihist[i] + 1));   // +1 self-loop
}

// ---------------- exclusive scan (3 kernels), 1024 elems / block ----------------
__global__ void scan_blocks(const int* __restrict__ ihist, int* __restrict__ row_ptr,
                            int* __restrict__ bsums, int N) {
  __shared__ int sh[256];
  int t = threadIdx.x;
  int base = blockIdx.x * 1024;
  int v[4];
  #pragma unroll
  for (int j = 0; j < 4; ++j) {
    int idx = base + t * 4 + j;
    v[j] = (idx < N) ? ihist[idx] : 0;
  }
  int local = v[0] + v[1] + v[2] + v[3];
  sh[t] = local;
  __syncthreads();
  for (int o = 1; o < 256; o <<= 1) {
    int x = (t >= o) ? sh[t - o] : 0;
    __syncthreads();
    sh[t] += x;
    __syncthreads();
  }
  int run = sh[t] - local;   // exclusive prefix of this thread's chunk
  #pragma unroll
  for (int j = 0; j < 4; ++j) {
    int idx = base + t * 4 + j;
    if (idx < N) row_ptr[idx] = run;
    run += v[j];
  }
  if (t == 255) bsums[blockIdx.x] = sh[255];
}

__global__ void scan_sums(int* __restrict__ bsums, int NB) {
  __shared__ int sh[256];
  int t = threadIdx.x;
  int v = (t < NB) ? bsums[t] : 0;
  sh[t] = v;
  __syncthreads();
  for (int o = 1; o < 256; o <<= 1) {
    int x = (t >= o) ? sh[t - o] : 0;
    __syncthreads();
    sh[t] += x;
    __syncthreads();
  }
  if (t < NB) bsums[t] = sh[t] - v;   // exclusive
}

__global__ void scan_add(int* __restrict__ row_ptr, const int* __restrict__ bsums,
                         int N, int E) {
  int i = blockIdx.x * blockDim.x + threadIdx.x;
  if (i < N) row_ptr[i] += bsums[i >> 10];
  if (i == N) row_ptr[N] = E;
}

// ---------------- CSR build ----------------
__global__ void build_csr(const int* __restrict__ ei, const int* __restrict__ row_ptr,
                          int* __restrict__ fill, const float* __restrict__ dinv,
                          int* __restrict__ col_s, float* __restrict__ norm_s, int E) {
  int e = blockIdx.x * blockDim.x + threadIdx.x;
  if (e >= E) return;
  int r = ei[e];
  int c = ei[E + e];
  int p = row_ptr[r] + atomicAdd(&fill[r], 1);
  col_s[p] = c;
  norm_s[p] = dinv[r] * dinv[c];
}

// ---------------- GEMM: Y[N][64] = X[N][K] @ W[K][64] ----------------
template <int K, int RPT>   // rows per block = 16*RPT
__global__ __launch_bounds__(256, 4) void gemm_nn(const float* __restrict__ X,
                                                  const float* __restrict__ Wg,
                                                  float* __restrict__ Y, int N) {
  constexpr int ROWS = 16 * RPT;
  __shared__ float ws[K * 64];
  __shared__ float xs[ROWS][K + 4];
  int t = threadIdx.x;
  int r0 = blockIdx.x * ROWS;
  for (int idx = t; idx < K * 64; idx += 256) ws[idx] = Wg[idx];
  for (int idx = t; idx < ROWS * K; idx += 256) {
    int r = idx / K, k = idx - r * K;
    int gr = r0 + r;
    xs[r][k] = (gr < N) ? X[(size_t)gr * K + k] : 0.f;
  }
  __syncthreads();
  int cg = t & 15;    // 16 col groups of 4
  int rg = t >> 4;    // 16 row groups of RPT
  float4 acc[RPT];
  #pragma unroll
  for (int i = 0; i < RPT; ++i) acc[i] = make_float4(0.f, 0.f, 0.f, 0.f);
  // R1: cap unrolling — full unroll (K/4 iters) spilled to scratch at K=128.
  #pragma unroll 2
  for (int k = 0; k < K; k += 4) {
    float4 wv0 = *(const float4*)&ws[(k + 0) * 64 + cg * 4];
    float4 wv1 = *(const float4*)&ws[(k + 1) * 64 + cg * 4];
    float4 wv2 = *(const float4*)&ws[(k + 2) * 64 + cg * 4];
    float4 wv3 = *(const float4*)&ws[(k + 3) * 64 + cg * 4];
    #pragma unroll
    for (int i = 0; i < RPT; ++i) {
      float4 xv = *(const float4*)&xs[rg * RPT + i][k];
      acc[i].x += xv.x * wv0.x + xv.y * wv1.x + xv.z * wv2.x + xv.w * wv3.x;
      acc[i].y += xv.x * wv0.y + xv.y * wv1.y + xv.z * wv2.y + xv.w * wv3.y;
      acc[i].z += xv.x * wv0.z + xv.y * wv1.z + xv.z * wv2.z + xv.w * wv3.z;
      acc[i].w += xv.x * wv0.w + xv.y * wv1.w + xv.z * wv2.w + xv.w * wv3.w;
    }
  }
  #pragma unroll
  for (int i = 0; i < RPT; ++i) {
    int gr = r0 + rg * RPT + i;
    if (gr < N) *(float4*)&Y[(size_t)gr * 64 + cg * 4] = acc[i];
  }
}

// ---------------- aggregation, H=64: one wave per node ----------------
__global__ __launch_bounds__(256) void agg64(const float* __restrict__ Y,
                                             const int* __restrict__ col_s,
                                             const float* __restrict__ norm_s,
                                             const int* __restrict__ row_ptr,
                                             const float* __restrict__ dinv,
                                             const float* __restrict__ bias,
                                             float* __restrict__ X, int relu, int N) {
  int i = blockIdx.x * 4 + (threadIdx.x >> 6);
  if (i >= N) return;
  int lane = threadIdx.x & 63;
  float di = dinv[i];
  float acc = di * di * Y[i * 64 + lane];
  float acc2 = 0.f;
  int p0 = row_ptr[i], p1 = row_ptr[i + 1];
  for (int base = p0; base < p1; base += 64) {
    int m = min(64, p1 - base);
    int c = 0; float nv = 0.f;
    if (lane < m) { c = col_s[base + lane]; nv = norm_s[base + lane]; }
    int j = 0;
    for (; j + 4 <= m; j += 4) {
      int c0 = __shfl(c, j),     c1 = __shfl(c, j + 1);
      int c2 = __shfl(c, j + 2), c3 = __shfl(c, j + 3);
      float n0 = __shfl(nv, j),     n1 = __shfl(nv, j + 1);
      float n2 = __shfl(nv, j + 2), n3 = __shfl(nv, j + 3);
      float y0 = Y[c0 * 64 + lane];
      float y1 = Y[c1 * 64 + lane];
      float y2 = Y[c2 * 64 + lane];
      float y3 = Y[c3 * 64 + lane];
      acc  += n0 * y0 + n1 * y1;
      acc2 += n2 * y2 + n3 * y3;
    }
    for (; j < m; ++j) {
      int cc = __shfl(c, j);
      float nn = __shfl(nv, j);
      acc += nn * Y[cc * 64 + lane];
    }
  }
  acc += acc2 + bias[lane];
  if (relu) acc = fmaxf(acc, 0.f);
  X[i * 64 + lane] = acc;
}

// ---------------- mean pooling partials ----------------
__global__ void mean_partial(const float* __restrict__ X, float* __restrict__ red, int N) {
  int lane = threadIdx.x & 63;
  int sub = threadIdx.x >> 6;     // 0..3
  int base = blockIdx.x * 1024;
  float s = 0.f;
  for (int r = sub; r < 1024; r += 4) {
    int row = base + r;
    if (row < N) s += X[row * 64 + lane];
  }
  __shared__ float sh[4][64];
  sh[sub][lane] = s;
  __syncthreads();
  if (sub == 0) {
    float t = sh[0][lane] + sh[1][lane] + sh[2][lane] + sh[3][lane];
    atomicAdd(&red[lane], t);
  }
}

// ---------------- h5 = X @ W5 (scalar per row) ----------------
__global__ void dot64(const float* __restrict__ X, const float* __restrict__ W5,
                      float* __restrict__ h5, int N) {
  int i = blockIdx.x * 4 + (threadIdx.x >> 6);
  if (i >= N) return;
  int lane = threadIdx.x & 63;
  float p = X[i * 64 + lane] * W5[lane];
  p = waveSum(p);
  if (lane == 0) h5[i] = p;
}

// ---------------- scalar aggregation (layer 5) ----------------
__global__ void agg_scalar(const float* __restrict__ h5, const int* __restrict__ col_s,
                           const float* __restrict__ norm_s, const int* __restrict__ row_ptr,
                           const float* __restrict__ dinv, const float* __restrict__ b5,
                           float* __restrict__ out, int N) {
  int i = blockIdx.x * blockDim.x + threadIdx.x;
  if (i >= N) return;
  float di = dinv[i];
  float acc = di * di * h5[i];
  int p1 = row_ptr[i + 1];
  for (int p = row_ptr[i]; p < p1; ++p) acc += norm_s[p] * h5[col_s[p]];
  out[i] = acc + b5[0];
}

// ---------------- heads: v and prob_nothing ----------------
__global__ void heads(const float* __restrict__ red, const float* __restrict__ Wv,
                      const float* __restrict__ bv, const float* __restrict__ Wdn,
                      const float* __restrict__ bdn, float* __restrict__ out, int N) {
  int lane = threadIdx.x;   // 64 threads
  float xm = red[lane] / (float)N;
  float pv = waveSum(xm * Wv[lane]);
  float pd = waveSum(xm * Wdn[lane]);
  if (lane == 0) {
    out[N] = pd + bdn[0];       // prob_nothing logit
    out[N + 1] = pv + bv[0];    // value head (final output slot)
  }
}

// ---------------- masked softmax over out[0..N] ----------------
__global__ void smax_max(const float* __restrict__ out, const int* __restrict__ ready,
                         float* __restrict__ red, int N) {
  int i = blockIdx.x * blockDim.x + threadIdx.x;
  float l = -3e38f;
  if (i < N) { if (ready[i]) l = out[i]; }
  else if (i == N) l = out[N];
  l = waveMax(l);
  __shared__ float sh[4];
  if (!(threadIdx.x & 63)) sh[threadIdx.x >> 6] = l;
  __syncthreads();
  if (threadIdx.x == 0) {
    float m = fmaxf(fmaxf(sh[0], sh[1]), fmaxf(sh[2], sh[3]));
    atomicMax(&((unsigned*)red)[65], encf(m));
  }
}

__global__ void smax_sum(const float* __restrict__ out, const int* __restrict__ ready,
                         float* __restrict__ red, int N) {
  float M = decf(((const unsigned*)red)[65]);
  int i = blockIdx.x * blockDim.x + threadIdx.x;
  float s = 0.f;
  if (i < N) { if (ready[i]) s = expf(out[i] - M); }
  else if (i == N) s = expf(out[N] - M);
  s = waveSum(s);
  __shared__ float sh[4];
  if (!(threadIdx.x & 63)) sh[threadIdx.x >> 6] = s;
  __syncthreads();
  if (threadIdx.x == 0) atomicAdd(&red[66], sh[0] + sh[1] + sh[2] + sh[3]);
}

__global__ void smax_write(float* __restrict__ out, const int* __restrict__ ready,
                           const float* __restrict__ red, int N) {
  float M = decf(((const unsigned*)red)[65]);
  float S = red[66];
  int i = blockIdx.x * blockDim.x + threadIdx.x;
  if (i < N) {
    out[i] = ready[i] ? (expf(out[i] - M) / S) : 0.f;
  } else if (i == N) {
    out[N] = expf(out[N] - M) / S;
  }
}

// ---------------------------------------------------------------------------
extern "C" void kernel_launch(void* const* d_in, const int* in_sizes, int n_in,
                              void* d_out, int out_size, void* d_ws, size_t ws_size,
                              hipStream_t stream) {
  const float* x    = (const float*)d_in[0];
  const int*   ei   = (const int*)d_in[1];
  const int*   ready= (const int*)d_in[2];
  const float* W1   = (const float*)d_in[3];
  const float* b1   = (const float*)d_in[4];
  const float* W2   = (const float*)d_in[5];
  const float* b2   = (const float*)d_in[6];
  const float* W3   = (const float*)d_in[7];
  const float* b3   = (const float*)d_in[8];
  const float* W4   = (const float*)d_in[9];
  const float* b4   = (const float*)d_in[10];
  const float* W5   = (const float*)d_in[11];
  const float* b5   = (const float*)d_in[12];
  const float* Wdn  = (const float*)d_in[13];
  const float* bdn  = (const float*)d_in[14];
  const float* Wv   = (const float*)d_in[15];
  const float* bv   = (const float*)d_in[16];
  float* out = (float*)d_out;

  int N = in_sizes[2];          // ready is (N,1)
  int E = in_sizes[1] / 2;      // edge_index is (2,E)

  // workspace carve (256B-aligned slices)
  char* base = (char*)d_ws;
  size_t off = 0;
  auto alloc = [&](size_t elems) -> void* {
    void* p = base + off;
    off += ((elems * 4 + 255) / 256) * 256;
    return p;
  };
  float* dinv   = (float*)alloc(N);
  int*   ihist  = (int*)alloc(N);
  int*   row_ptr= (int*)alloc((size_t)N + 1);
  int*   bsums  = (int*)alloc(256);
  int*   col_s  = (int*)alloc(E);
  float* norm_s = (float*)alloc(E);
  float* h5     = (float*)alloc(N);
  float* red    = (float*)alloc(128);
  float* Yb     = (float*)alloc((size_t)N * 64);
  float* Xb     = (float*)alloc((size_t)N * 64);
  (void)ws_size; (void)n_in; (void)out_size;

  int NB = (N + 1023) / 1024;
  int gE = (E + 255) / 256;
  int gN = (N + 255) / 256;
  int gN1 = (N + 1 + 255) / 256;
  int gW = (N + 3) / 4;         // wave-per-node grids

  hipMemsetAsync(ihist, 0, (size_t)N * 4, stream);
  init_red<<<1, 128, 0, stream>>>(red);
  hist_k<<<gE, 256, 0, stream>>>(ei, ihist, E);
  dinv_k<<<gN, 256, 0, stream>>>(ihist, dinv, N);
  scan_blocks<<<NB, 256, 0, stream>>>(ihist, row_ptr, bsums, N);
  scan_sums<<<1, 256, 0, stream>>>(bsums, NB);
  scan_add<<<gN1, 256, 0, stream>>>(row_ptr, bsums, N, E);
  hipMemsetAsync(ihist, 0, (size_t)N * 4, stream);
  build_csr<<<gE, 256, 0, stream>>>(ei, row_ptr, ihist, dinv, col_s, norm_s, E);

  // layer 1 (K = 128)
  gemm_nn<128, 2><<<(N + 31) / 32, 256, 0, stream>>>(x, W1, Yb, N);
  agg64<<<gW, 256, 0, stream>>>(Yb, col_s, norm_s, row_ptr, dinv, b1, Xb, 1, N);
  // layers 2-4 (K = 64)
  gemm_nn<64, 4><<<(N + 63) / 64, 256, 0, stream>>>(Xb, W2, Yb, N);
  agg64<<<gW, 256, 0, stream>>>(Yb, col_s, norm_s, row_ptr, dinv, b2, Xb, 1, N);
  gemm_nn<64, 4><<<(N + 63) / 64, 256, 0, stream>>>(Xb, W3, Yb, N);
  agg64<<<gW, 256, 0, stream>>>(Yb, col_s, norm_s, row_ptr, dinv, b3, Xb, 1, N);
  gemm_nn<64, 4><<<(N + 63) / 64, 256, 0, stream>>>(Xb, W4, Yb, N);
  agg64<<<gW, 256, 0, stream>>>(Yb, col_s, norm_s, row_ptr, dinv, b4, Xb, 1, N);

  // pooled heads + layer 5
  mean_partial<<<NB, 256, 0, stream>>>(Xb, red, N);
  dot64<<<gW, 256, 0, stream>>>(Xb, W5, h5, N);
  agg_scalar<<<gN, 256, 0, stream>>>(h5, col_s, norm_s, row_ptr, dinv, b5, out, N);
  heads<<<1, 64, 0, stream>>>(red, Wv, bv, Wdn, bdn, out, N);

  // masked softmax over out[0..N]
  smax_max<<<gN1, 256, 0, stream>>>(out, ready, red, N);
  smax_sum<<<gN1, 256, 0, stream>>>(out, ready, red, N);
  smax_write<<<gN1, 256, 0, stream>>>(out, ready, red, N);
}